// Round 6
// baseline (533.479 us; speedup 1.0000x reference)
//
#include <hip/hip_runtime.h>
#include <hip/hip_bf16.h>

// ---------------------------------------------------------------------------
// GumbelNeRF fused kernel, round 12: complete register diet + LDS conflict pads.
//
// R9/R11 post-mortem: identical 84/84 reg split + 84MB spill writes despite
// phase-A/pass-1 diet => the register peak is PASS 2A (32 hoisted f16x8
// weight frags = 128 VGPR) and pass 2b (20 frags = 80), untouched so far.
// R12:
//  - pass 2a: jt loop split 2x4 with asm fence between halves (16 frags in
//    flight); pass 2b: nt loop split 2x2 (10 frags in flight).
//  - keep phase-A mt-halves split, Ah[4][3] hoist, launch_bounds(256,3).
//  - LDS row strides padded to odd-dword: sY 136->138 hw, sPE 72->74 hw
//    (R11 bank conflicts 12.3M from stride = 4 mod 32). SMEM 41216, 3 blocks OK.
// Sigma numerics unchanged: f16 3-product split (hi + lo/2048), fp32
// accumulate, threefry gumbel, atomic sRed reduction.
// ---------------------------------------------------------------------------

#define NPTS 131072
#define PT 64
#define NTH 256
#define NBLK (NPTS / PT)
#define INV2048 (1.0f / 2048.0f)

// ws sections (f16 element offsets) — identical to rounds 2-11
#define WS_ENC_H 0
#define WS_ENC_L 8192
#define WS_SH_H  16384
#define WS_SH_L  147456
#define WS_R1_H  278528

// LDS byte offsets, total 41216
// sYh [64][138] f16 = 17664 ; later sH [64][69] f32 (17664)
// OFF_B region 21504: sPEh[64][74](9472)+sPEl(9472) | sYl[64][138](17664) | sSB[64][168](21504)
// sRed [8][64] f32 = 2048
#define OFF_YH   0
#define OFF_B    17664
#define OFF_RED  39168
#define SMEM_SZ  41216

// smalls live in sSB row-pad (cols 160..167 = bytes 320..335 of each 336B row)
#define S_LIST(s) (*(int*)(smem + OFF_B + (s) * 336 + 320))
#define S_BID(p)  (*(int*)(smem + OFF_B + (p) * 336 + 324))
#define S_CNT(e)  (*(int*)(smem + OFF_B + (e) * 336 + 328))
#define S_OFF(e)  (*(int*)(smem + OFF_B + (e) * 336 + 332))

typedef __attribute__((ext_vector_type(8))) _Float16 f16x8;
typedef __attribute__((ext_vector_type(4))) _Float16 f16x4;
typedef __attribute__((ext_vector_type(4))) float f32x4;

#define MFMA(a, b, c) __builtin_amdgcn_mfma_f32_16x16x32_f16((a), (b), (c), 0, 0, 0)

__device__ __forceinline__ unsigned rotl32(unsigned x, int d) {
  return (x << d) | (x >> (32 - d));
}

// JAX threefry2x32, keys (0,42), counter (0, flat), partitionable fold.
__device__ __forceinline__ float gumbel_for(unsigned flat) {
  const unsigned k0 = 0u, k1 = 42u;
  const unsigned ks2 = k0 ^ k1 ^ 0x1BD11BDAu;
  unsigned x0 = 0u + k0;
  unsigned x1 = flat + k1;
#define TF_RND(r) { x0 += x1; x1 = rotl32(x1, r); x1 ^= x0; }
  TF_RND(13) TF_RND(15) TF_RND(26) TF_RND(6)
  x0 += k1;  x1 += ks2 + 1u;
  TF_RND(17) TF_RND(29) TF_RND(16) TF_RND(24)
  x0 += ks2; x1 += k0 + 2u;
  TF_RND(13) TF_RND(15) TF_RND(26) TF_RND(6)
  x0 += k0;  x1 += k1 + 3u;
  TF_RND(17) TF_RND(29) TF_RND(16) TF_RND(24)
  x0 += k1;  x1 += ks2 + 4u;
  TF_RND(13) TF_RND(15) TF_RND(26) TF_RND(6)
  x0 += ks2; x1 += k0 + 5u;
#undef TF_RND
  unsigned bits = x0 ^ x1;
  float u = __uint_as_float((bits >> 9) | 0x3f800000u) - 1.0f;
  return -logf(-logf(u + 1e-20f) + 1e-20f);
}

// ---------------------------------------------------------------------------
// prep: fp32 weights -> fragment-linear f16 (scaled split) in ws  [unchanged]
// ---------------------------------------------------------------------------
__global__ void prep_kernel(const float* __restrict__ W_enc,
                            const float* __restrict__ W_sh,
                            const float* __restrict__ W_r1,
                            _Float16* __restrict__ ws) {
  int idx = blockIdx.x * 256 + threadIdx.x;
  if (idx < 8192) {
    int tile = idx >> 9, r = idx & 511;
    int L = r >> 3, j = r & 7;
    int nt = tile >> 1, kt = tile & 1;
    int k = kt * 32 + (L >> 4) * 8 + j;
    int n = nt * 16 + (L & 15);
    float v = (k < 63) ? W_enc[k * 128 + n] : 0.0f;
    _Float16 h = (_Float16)v;
    ws[WS_ENC_H + idx] = h;
    ws[WS_ENC_L + idx] = (_Float16)((v - (float)h) * 2048.0f);
  } else if (idx < 8192 + 131072) {
    int s = idx - 8192;
    int tile = s >> 9, r = s & 511;
    int L = r >> 3, j = r & 7;
    int e = tile >> 5, nt = (tile >> 2) & 7, kt = tile & 3;
    int k = kt * 32 + (L >> 4) * 8 + j;
    int n = nt * 16 + (L & 15);
    float v = W_sh[e * 16384 + k * 128 + n];
    _Float16 h = (_Float16)v;
    ws[WS_SH_H + s] = h;
    ws[WS_SH_L + s] = (_Float16)((v - (float)h) * 2048.0f);
  } else if (idx < 8192 + 131072 + 81920) {
    int s = idx - (8192 + 131072);
    int tile = s >> 9, r = s & 511;
    int L = r >> 3, j = r & 7;
    int e = tile / 20, rr = tile % 20;
    int nt = rr / 5, kt = rr % 5;
    int k = kt * 32 + (L >> 4) * 8 + j;
    int n = nt * 16 + (L & 15);
    float v = (k < 155) ? W_r1[e * 9920 + k * 64 + n] : 0.0f;
    ws[WS_R1_H + s] = (_Float16)v;
  }
}

// ---------------------------------------------------------------------------
__global__ __launch_bounds__(NTH, 3)
void nerf_moe_kernel(const float* __restrict__ x,
                     const float* __restrict__ b_enc,
                     const float* __restrict__ b_sh,
                     const float* __restrict__ w_sig, const float* __restrict__ b_sig,
                     const float* __restrict__ b_r1,
                     const float* __restrict__ W_r2,  const float* __restrict__ b_r2,
                     const _Float16* __restrict__ wsw,
                     float* __restrict__ out) {
  __shared__ __align__(16) unsigned char smem[SMEM_SZ];
  _Float16* sYh  = (_Float16*)(smem + OFF_YH);   // [64][138]
  float*    sH   = (float*)(smem + OFF_YH);      // [64][69]
  _Float16* sYl  = (_Float16*)(smem + OFF_B);    // [64][138]
  _Float16* sPEh = (_Float16*)(smem + OFF_B);    // [64][74]
  _Float16* sPEl = (_Float16*)(smem + OFF_B + 9472);
  _Float16* sSB  = (_Float16*)(smem + OFF_B);    // [64][168]
  float*    sRed = (float*)(smem + OFF_RED);     // [8][64] atomic

  const int t  = threadIdx.x;
  const int w  = t >> 6;        // wave id 0..3
  const int L  = t & 63;        // lane
  const int q  = L >> 4;        // quad 0..3
  const int c  = L & 15;
  const int n0 = blockIdx.x * PT;

  // zero the atomic sigma-reduction buffer (ordered vs pass 1 by barriers 1-3)
  sRed[t] = 0.0f;
  sRed[t + 256] = 0.0f;

  // ---- phase 0: xyz positional encoding ----
  for (int idx = t; idx < PT * 64; idx += NTH) {
    int p = idx >> 6, f = idx & 63;
    const float* xr = x + (size_t)(n0 + p) * 6;
    float v;
    if (f < 3)       v = xr[f];
    else if (f < 33) { int g = f - 3;  v = sinf(xr[g % 3] * (float)(1 << (g / 3))); }
    else if (f < 63) { int g = f - 33; v = cosf(xr[g % 3] * (float)(1 << (g / 3))); }
    else             v = 0.0f;
    _Float16 h = (_Float16)v;
    sPEh[p * 74 + f] = h;
    sPEl[p * 74 + f] = (_Float16)((v - (float)h) * 2048.0f);
  }
  __syncthreads();                                   // (1)

  // ---- phase A: Y = relu(PE @ W_enc + b) via MFMA, mt split in halves ----
  {
    f16x8 beh[2][2], bel[2][2];
    #pragma unroll
    for (int ntL = 0; ntL < 2; ++ntL)
      #pragma unroll
      for (int kt = 0; kt < 2; ++kt) {
        int tile = (2 * w + ntL) * 2 + kt;
        beh[ntL][kt] = *(const f16x8*)(wsw + WS_ENC_H + tile * 512 + L * 8);
        bel[ntL][kt] = *(const f16x8*)(wsw + WS_ENC_L + tile * 512 + L * 8);
      }
    f32x4 a1[4][2], a2[4][2];
    #pragma unroll
    for (int mt = 0; mt < 4; ++mt)
      #pragma unroll
      for (int ntL = 0; ntL < 2; ++ntL) { a1[mt][ntL] = (f32x4)0.0f; a2[mt][ntL] = (f32x4)0.0f; }
    // two halves over mt; pah/pal registers reused between halves
    #pragma unroll
    for (int half = 0; half < 2; ++half) {
      f16x8 pah[2][2], pal[2][2];
      #pragma unroll
      for (int m = 0; m < 2; ++m)
        #pragma unroll
        for (int kt = 0; kt < 2; ++kt) {
          int off = ((half * 2 + m) * 16 + c) * 74 + kt * 32 + q * 8;
          pah[m][kt] = *(const f16x8*)(sPEh + off);
          pal[m][kt] = *(const f16x8*)(sPEl + off);
        }
      #pragma unroll
      for (int kt = 0; kt < 2; ++kt)
        #pragma unroll
        for (int m = 0; m < 2; ++m)
          #pragma unroll
          for (int ntL = 0; ntL < 2; ++ntL) {
            int mt = half * 2 + m;
            a1[mt][ntL] = MFMA(pah[m][kt], beh[ntL][kt], a1[mt][ntL]);
            a2[mt][ntL] = MFMA(pah[m][kt], bel[ntL][kt], a2[mt][ntL]);
            a2[mt][ntL] = MFMA(pal[m][kt], beh[ntL][kt], a2[mt][ntL]);
          }
      asm volatile("" ::: "memory");   // fence: keep halves' LDS loads apart
    }
    __syncthreads();                                 // (2) sPE reads done -> sYl writable
    float bb0 = b_enc[(2 * w) * 16 + c];
    float bb1 = b_enc[(2 * w + 1) * 16 + c];
    #pragma unroll
    for (int mt = 0; mt < 4; ++mt)
      #pragma unroll
      for (int ntL = 0; ntL < 2; ++ntL) {
        float bb = ntL ? bb1 : bb0;
        int col = (2 * w + ntL) * 16 + c;
        #pragma unroll
        for (int r = 0; r < 4; ++r) {
          float v = fmaxf(a1[mt][ntL][r] + a2[mt][ntL][r] * INV2048 + bb, 0.0f);
          int row = mt * 16 + q * 4 + r;
          _Float16 h = (_Float16)v;
          sYh[row * 138 + col] = h;
          sYl[row * 138 + col] = (_Float16)((v - (float)h) * 2048.0f);
        }
      }
  }
  __syncthreads();                                   // (3)

  // hoist Y hi frags for kt=0..2 only (48 VGPR); kt=3 + all lo re-read per use
  f16x8 Ah[4][3];
  #pragma unroll
  for (int nt = 0; nt < 4; ++nt)
    #pragma unroll
    for (int kt = 0; kt < 3; ++kt)
      Ah[nt][kt] = *(const f16x8*)(sYh + (nt * 16 + c) * 138 + kt * 32 + q * 8);
  const f32x4 wsv0 = *(const f32x4*)(w_sig + (2 * w) * 16 + q * 4);
  const f32x4 wsv1 = *(const f32x4*)(w_sig + (2 * w + 1) * 16 + q * 4);

  // ---- pass 1: 16-step (e,i) loop, single-buffered weights ----
  float psum[4] = {0.f, 0.f, 0.f, 0.f};

  #pragma unroll 1
  for (int s = 0; s < 16; ++s) {
    int e = s >> 1, i = s & 1;
    int tbase = (e * 8 + 2 * w + i) * 4;
    f16x8 bh[4], bl[4];
    #pragma unroll
    for (int kt = 0; kt < 4; ++kt) {
      bh[kt] = *(const f16x8*)(wsw + WS_SH_H + (tbase + kt) * 512 + L * 8);
      bl[kt] = *(const f16x8*)(wsw + WS_SH_L + (tbase + kt) * 512 + L * 8);
    }
    f32x4 bb = *(const f32x4*)(b_sh + e * 128 + (2 * w + i) * 16 + q * 4);

    f32x4 a1[4], a2[4];
    #pragma unroll
    for (int nt = 0; nt < 4; ++nt) { a1[nt] = (f32x4)0.0f; a2[nt] = (f32x4)0.0f; }
    #pragma unroll
    for (int kt = 0; kt < 4; ++kt)
      #pragma unroll
      for (int nt = 0; nt < 4; ++nt) {
        f16x8 al = *(const f16x8*)(sYl + (nt * 16 + c) * 138 + kt * 32 + q * 8);
        f16x8 ah;
        if (kt < 3) ah = Ah[nt][kt];
        else        ah = *(const f16x8*)(sYh + (nt * 16 + c) * 138 + kt * 32 + q * 8);
        a1[nt] = MFMA(bh[kt], ah, a1[nt]);
        a2[nt] = MFMA(bl[kt], ah, a2[nt]);
        a2[nt] = MFMA(bh[kt], al, a2[nt]);
      }
    f32x4 wv = (s & 1) ? wsv1 : wsv0;
    #pragma unroll
    for (int nt = 0; nt < 4; ++nt)
      #pragma unroll
      for (int r = 0; r < 4; ++r) {
        float sv = fmaxf(fmaf(a2[nt][r], INV2048, a1[nt][r]) + bb[r], 0.0f);
        psum[nt] = fmaf(sv, wv[r], psum[nt]);
      }
    if (s & 1) {                       // end of expert e
      #pragma unroll
      for (int nt = 0; nt < 4; ++nt) {
        float v = psum[nt];
        v += __shfl_xor(v, 16);
        v += __shfl_xor(v, 32);
        if (q == 0) atomicAdd(sRed + e * 64 + nt * 16 + c, v);
        psum[nt] = 0.f;
      }
    }
  }
  __syncthreads();                                   // (4) — only pass-1 barrier

  // ---- argmax: distributed, 4 threads/point x 2 experts, gumbel inline ----
  {
    int pt = t >> 2;
    int eb = (t & 3) * 2;
    float best = -1e30f, bsig = 0.0f;
    int bide = 0;
    const float bs = b_sig[0];
    #pragma unroll
    for (int j = 0; j < 2; ++j) {
      int e = eb + j;
      float s = sRed[e * 64 + pt];
      float dotv = s + bs;
      float sig = fmaxf(dotv, 0.0f) + log1pf(expf(-fabsf(dotv)));
      float z = logf(sig + 1e-10f) / 0.166667f;
      float score = z + gumbel_for((unsigned)((n0 + pt) * 8 + e));
      if (score > best) { best = score; bsig = sig; bide = e; }
    }
    #pragma unroll
    for (int m = 1; m <= 2; m <<= 1) {
      float oS  = __shfl_xor(best, m);
      float oSg = __shfl_xor(bsig, m);
      int   oI  = __shfl_xor(bide, m);
      if (oS > best || (oS == best && oI < bide)) { best = oS; bsig = oSg; bide = oI; }
    }
    if ((t & 3) == 0) {
      S_BID(pt) = bide;                // row-pad slot; sYl dead, sSB not yet
      out[(size_t)(n0 + pt) * 4 + 3] = bsig;
    }
  }
  __syncthreads();                                   // (5)

  // ---- bucket lists ----
  if (t < 8) {
    int cnt = 0;
    for (int p = 0; p < PT; ++p) cnt += (S_BID(p) == t);
    S_CNT(t) = cnt;
  }
  __syncthreads();                                   // (6)
  if (t < 8) {
    int off = 0;
    for (int i = 0; i < t; ++i) off += S_CNT(i);
    S_OFF(t) = off;
    int k = off;
    for (int p = 0; p < PT; ++p) if (S_BID(p) == t) { S_LIST(k) = p; k++; }
  }
  __syncthreads();                                   // (7)

  // ---- pass 2a: viewdir PE into sSB + winner S recompute (transposed) ----
  for (int idx = t; idx < PT * 32; idx += NTH) {
    int s = idx >> 5, cc = idx & 31;
    int pt = S_LIST(s);
    const float* xr = x + (size_t)(n0 + pt) * 6 + 3;
    float v;
    if (cc < 3)       v = xr[cc];
    else if (cc < 15) { int g = cc - 3;  v = sinf(xr[g % 3] * (float)(1 << (g / 3))); }
    else if (cc < 27) { int g = cc - 15; v = cosf(xr[g % 3] * (float)(1 << (g / 3))); }
    else              v = 0.0f;
    sSB[s * 168 + 128 + cc] = (_Float16)v;
  }
  #pragma unroll 1
  for (int ei = 0; ei < 2; ++ei) {
    int e = 2 * w + ei;
    int cnt = S_CNT(e), off = S_OFF(e);
    for (int base = 0; base < cnt; base += 16) {
      int sidx = base + c; if (sidx >= cnt) sidx = cnt - 1;
      int pt = S_LIST(off + sidx);
      f16x8 yb[4];
      #pragma unroll
      for (int kt = 0; kt < 4; ++kt)
        yb[kt] = *(const f16x8*)(sYh + pt * 138 + kt * 32 + q * 8);
      f32x4 acc[8];
      #pragma unroll
      for (int jt = 0; jt < 8; ++jt) acc[jt] = (f32x4)0.0f;
      // jt split into 2 halves of 4: <=16 weight frags in flight (64 VGPR)
      #pragma unroll
      for (int jh = 0; jh < 2; ++jh) {
        #pragma unroll
        for (int jt2 = 0; jt2 < 4; ++jt2) {
          int jt = jh * 4 + jt2;
          #pragma unroll
          for (int kt = 0; kt < 4; ++kt) {
            f16x8 a = *(const f16x8*)(wsw + WS_SH_H + ((e * 8 + jt) * 4 + kt) * 512 + L * 8);
            acc[jt] = MFMA(a, yb[kt], acc[jt]);
          }
        }
        asm volatile("" ::: "memory"); // fence: limit weight-load hoisting
      }
      bool wr = (base + c) < cnt;
      int slot = off + base + c;
      #pragma unroll
      for (int jt = 0; jt < 8; ++jt) {
        f32x4 bb = *(const f32x4*)(b_sh + e * 128 + jt * 16 + q * 4);
        f16x4 v;
        #pragma unroll
        for (int r = 0; r < 4; ++r)
          v[r] = (_Float16)fmaxf(acc[jt][r] + bb[r], 0.0f);
        if (wr) *(f16x4*)(sSB + slot * 168 + jt * 16 + q * 4) = v;
      }
    }
  }
  __syncthreads();                                   // (8) sYh dead -> sH writable

  // ---- pass 2b: rgb layer 1 via MFMA ([S;vd] @ W_r1) ----
  #pragma unroll 1
  for (int ei = 0; ei < 2; ++ei) {
    int e = 2 * w + ei;
    int cnt = S_CNT(e), off = S_OFF(e);
    for (int base = 0; base < cnt; base += 16) {
      int sidx = base + c; if (sidx >= cnt) sidx = cnt - 1;
      int slot = off + sidx;
      f16x8 ag[5];
      #pragma unroll
      for (int kt = 0; kt < 5; ++kt)
        ag[kt] = *(const f16x8*)(sSB + slot * 168 + kt * 32 + q * 8);
      f32x4 hacc[4];
      #pragma unroll
      for (int nt = 0; nt < 4; ++nt) hacc[nt] = (f32x4)0.0f;
      // nt split into 2 halves of 2: <=10 weight frags in flight (40 VGPR)
      #pragma unroll
      for (int nh = 0; nh < 2; ++nh) {
        #pragma unroll
        for (int nt2 = 0; nt2 < 2; ++nt2) {
          int nt = nh * 2 + nt2;
          #pragma unroll
          for (int kt = 0; kt < 5; ++kt) {
            f16x8 bf = *(const f16x8*)(wsw + WS_R1_H + ((e * 4 + nt) * 5 + kt) * 512 + L * 8);
            hacc[nt] = MFMA(ag[kt], bf, hacc[nt]);
          }
        }
        asm volatile("" ::: "memory"); // fence: limit weight-load hoisting
      }
      #pragma unroll
      for (int nt = 0; nt < 4; ++nt) {
        float bb = b_r1[e * 64 + nt * 16 + c];
        #pragma unroll
        for (int r = 0; r < 4; ++r) {
          int m = q * 4 + r;
          if (base + m < cnt)
            sH[(off + base + m) * 69 + nt * 16 + c] = fmaxf(hacc[nt][r] + bb, 0.0f);
        }
      }
    }
  }
  __syncthreads();                                   // (9)

  // ---- layer 2: rgb = sigmoid(h @ W_r2 + b) ----
  if (t < 192) {
    int s = t / 3, o = t - s * 3;
    int pt = S_LIST(s);
    int e = S_BID(pt);
    float a = b_r2[e * 3 + o];
    const float* w2 = W_r2 + e * 192 + o;
    #pragma unroll
    for (int jj = 0; jj < 64; jj += 4) {
      f32x4 h4 = *(const f32x4*)(sH + s * 69 + jj);
      a = fmaf(h4.x, w2[jj * 3], a);
      a = fmaf(h4.y, w2[jj * 3 + 3], a);
      a = fmaf(h4.z, w2[jj * 3 + 6], a);
      a = fmaf(h4.w, w2[jj * 3 + 9], a);
    }
    out[(size_t)(n0 + pt) * 4 + o] = 1.0f / (1.0f + expf(-a));
  }
}

extern "C" void kernel_launch(void* const* d_in, const int* in_sizes, int n_in,
                              void* d_out, int out_size, void* d_ws, size_t ws_size,
                              hipStream_t stream) {
  (void)in_sizes; (void)n_in; (void)ws_size; (void)out_size;
  const float* x     = (const float*)d_in[0];
  const float* W_enc = (const float*)d_in[1];
  const float* b_enc = (const float*)d_in[2];
  const float* W_sh  = (const float*)d_in[3];
  const float* b_sh  = (const float*)d_in[4];
  const float* w_sig = (const float*)d_in[5];
  const float* b_sig = (const float*)d_in[6];
  const float* W_r1  = (const float*)d_in[7];
  const float* b_r1  = (const float*)d_in[8];
  const float* W_r2  = (const float*)d_in[9];
  const float* b_r2  = (const float*)d_in[10];
  _Float16* ws = (_Float16*)d_ws;     // needs 720896 B
  float* outp = (float*)d_out;
  prep_kernel<<<864, 256, 0, stream>>>(W_enc, W_sh, W_r1, ws);
  nerf_moe_kernel<<<NBLK, NTH, 0, stream>>>(x, b_enc, b_sh, w_sig, b_sig,
                                            b_r1, W_r2, b_r2, ws, outp);
}

// Round 7
// 260.890 us; speedup vs baseline: 2.0448x; 2.0448x over previous
//
#include <hip/hip_runtime.h>
#include <hip/hip_bf16.h>

// ---------------------------------------------------------------------------
// GumbelNeRF fused kernel, round 13: champion base (R7, 235us) + setprio +
// ballot bucket build.
//
// R8-R12 post-mortem: all 3-blocks/CU attempts lost to the 2-block champion.
// Demand ~188 regs: capping to 168 spills (250us, R9/R11); fencing to fit
// serializes (R12); and R12's odd-dword LDS "conflict pads" broke 16B
// alignment of ds_read_b128 (strides 272B->276B), 4x'ing LDS ops (503us).
// Bank conflicts at 6.4M cycles are ~0.004% of the dispatch - a non-issue.
//
// R13 = byte-identical R7 structure (launch_bounds(256,2), LDS 47104,
// dbuf pass 1, sRedE cross-wave reduction) plus ONLY:
//  - s_setprio(1/0) around MFMA clusters (2 independent blocks/CU ->
//    priority arbitration has something to do; attn-regime +4-7%).
//  - wave-0 ballot/popc bucket build, replacing two serial t<8 scan loops
//    and one barrier (~2-4us).
// Sigma numerics unchanged: f16 3-product split (hi + lo/2048), fp32
// accumulate, threefry gumbel.
// ---------------------------------------------------------------------------

#define NPTS 131072
#define PT 64
#define NTH 256
#define NBLK (NPTS / PT)
#define INV2048 (1.0f / 2048.0f)

// ws sections (f16 element offsets) — identical to rounds 2-7
#define WS_ENC_H 0
#define WS_ENC_L 8192
#define WS_SH_H  16384
#define WS_SH_L  147456
#define WS_R1_H  278528

// LDS byte offsets, total 47104
#define OFF_YH   0      // sYh [64][136] f16 = 17408 ; pass2b+: sH [64][68] f32
#define OFF_B    17408  // 21504 B: sPEh[64][72](9216)+sPEl(9216) | sYl[64][136] | sSB[64][168] f16
#define OFF_RED  38912  // sRedE [8][4][64] f32 = 8192
#define SMEM_SZ  47104

// smalls live in sSB row-pad (cols 160..167 = bytes 320..335 of each 336B row)
#define S_LIST(s) (*(int*)(smem + OFF_B + (s) * 336 + 320))
#define S_BID(p)  (*(int*)(smem + OFF_B + (p) * 336 + 324))
#define S_CNT(e)  (*(int*)(smem + OFF_B + (e) * 336 + 328))
#define S_OFF(e)  (*(int*)(smem + OFF_B + (e) * 336 + 332))

typedef __attribute__((ext_vector_type(8))) _Float16 f16x8;
typedef __attribute__((ext_vector_type(4))) _Float16 f16x4;
typedef __attribute__((ext_vector_type(4))) float f32x4;

#define MFMA(a, b, c) __builtin_amdgcn_mfma_f32_16x16x32_f16((a), (b), (c), 0, 0, 0)

__device__ __forceinline__ unsigned rotl32(unsigned x, int d) {
  return (x << d) | (x >> (32 - d));
}

// JAX threefry2x32, keys (0,42), counter (0, flat), partitionable fold.
__device__ __forceinline__ float gumbel_for(unsigned flat) {
  const unsigned k0 = 0u, k1 = 42u;
  const unsigned ks2 = k0 ^ k1 ^ 0x1BD11BDAu;
  unsigned x0 = 0u + k0;
  unsigned x1 = flat + k1;
#define TF_RND(r) { x0 += x1; x1 = rotl32(x1, r); x1 ^= x0; }
  TF_RND(13) TF_RND(15) TF_RND(26) TF_RND(6)
  x0 += k1;  x1 += ks2 + 1u;
  TF_RND(17) TF_RND(29) TF_RND(16) TF_RND(24)
  x0 += ks2; x1 += k0 + 2u;
  TF_RND(13) TF_RND(15) TF_RND(26) TF_RND(6)
  x0 += k0;  x1 += k1 + 3u;
  TF_RND(17) TF_RND(29) TF_RND(16) TF_RND(24)
  x0 += k1;  x1 += ks2 + 4u;
  TF_RND(13) TF_RND(15) TF_RND(26) TF_RND(6)
  x0 += ks2; x1 += k0 + 5u;
#undef TF_RND
  unsigned bits = x0 ^ x1;
  float u = __uint_as_float((bits >> 9) | 0x3f800000u) - 1.0f;
  return -logf(-logf(u + 1e-20f) + 1e-20f);
}

// ---------------------------------------------------------------------------
// prep: fp32 weights -> fragment-linear f16 (scaled split) in ws  [unchanged]
// ---------------------------------------------------------------------------
__global__ void prep_kernel(const float* __restrict__ W_enc,
                            const float* __restrict__ W_sh,
                            const float* __restrict__ W_r1,
                            _Float16* __restrict__ ws) {
  int idx = blockIdx.x * 256 + threadIdx.x;
  if (idx < 8192) {
    int tile = idx >> 9, r = idx & 511;
    int L = r >> 3, j = r & 7;
    int nt = tile >> 1, kt = tile & 1;
    int k = kt * 32 + (L >> 4) * 8 + j;
    int n = nt * 16 + (L & 15);
    float v = (k < 63) ? W_enc[k * 128 + n] : 0.0f;
    _Float16 h = (_Float16)v;
    ws[WS_ENC_H + idx] = h;
    ws[WS_ENC_L + idx] = (_Float16)((v - (float)h) * 2048.0f);
  } else if (idx < 8192 + 131072) {
    int s = idx - 8192;
    int tile = s >> 9, r = s & 511;
    int L = r >> 3, j = r & 7;
    int e = tile >> 5, nt = (tile >> 2) & 7, kt = tile & 3;
    int k = kt * 32 + (L >> 4) * 8 + j;
    int n = nt * 16 + (L & 15);
    float v = W_sh[e * 16384 + k * 128 + n];
    _Float16 h = (_Float16)v;
    ws[WS_SH_H + s] = h;
    ws[WS_SH_L + s] = (_Float16)((v - (float)h) * 2048.0f);
  } else if (idx < 8192 + 131072 + 81920) {
    int s = idx - (8192 + 131072);
    int tile = s >> 9, r = s & 511;
    int L = r >> 3, j = r & 7;
    int e = tile / 20, rr = tile % 20;
    int nt = rr / 5, kt = rr % 5;
    int k = kt * 32 + (L >> 4) * 8 + j;
    int n = nt * 16 + (L & 15);
    float v = (k < 155) ? W_r1[e * 9920 + k * 64 + n] : 0.0f;
    ws[WS_R1_H + s] = (_Float16)v;
  }
}

// ---------------------------------------------------------------------------
__global__ __launch_bounds__(NTH, 2)
void nerf_moe_kernel(const float* __restrict__ x,
                     const float* __restrict__ b_enc,
                     const float* __restrict__ b_sh,
                     const float* __restrict__ w_sig, const float* __restrict__ b_sig,
                     const float* __restrict__ b_r1,
                     const float* __restrict__ W_r2,  const float* __restrict__ b_r2,
                     const _Float16* __restrict__ wsw,
                     float* __restrict__ out) {
  __shared__ __align__(16) unsigned char smem[SMEM_SZ];
  _Float16* sYh  = (_Float16*)(smem + OFF_YH);
  float*    sH   = (float*)(smem + OFF_YH);
  _Float16* sYl  = (_Float16*)(smem + OFF_B);
  _Float16* sPEh = (_Float16*)(smem + OFF_B);
  _Float16* sPEl = (_Float16*)(smem + OFF_B + 9216);
  _Float16* sSB  = (_Float16*)(smem + OFF_B);
  float*    sRedE = (float*)(smem + OFF_RED);   // [8][4][64]

  const int t  = threadIdx.x;
  const int w  = t >> 6;        // wave id 0..3
  const int L  = t & 63;        // lane
  const int q  = L >> 4;        // quad 0..3
  const int c  = L & 15;
  const int n0 = blockIdx.x * PT;

  // ---- phase 0: xyz positional encoding ----
  for (int idx = t; idx < PT * 64; idx += NTH) {
    int p = idx >> 6, f = idx & 63;
    const float* xr = x + (size_t)(n0 + p) * 6;
    float v;
    if (f < 3)       v = xr[f];
    else if (f < 33) { int g = f - 3;  v = sinf(xr[g % 3] * (float)(1 << (g / 3))); }
    else if (f < 63) { int g = f - 33; v = cosf(xr[g % 3] * (float)(1 << (g / 3))); }
    else             v = 0.0f;
    _Float16 h = (_Float16)v;
    sPEh[p * 72 + f] = h;
    sPEl[p * 72 + f] = (_Float16)((v - (float)h) * 2048.0f);
  }
  __syncthreads();                                   // (1)

  // ---- phase A: Y = relu(PE @ W_enc + b) via MFMA ----
  {
    f16x8 beh[2][2], bel[2][2];
    #pragma unroll
    for (int ntL = 0; ntL < 2; ++ntL)
      #pragma unroll
      for (int kt = 0; kt < 2; ++kt) {
        int tile = (2 * w + ntL) * 2 + kt;
        beh[ntL][kt] = *(const f16x8*)(wsw + WS_ENC_H + tile * 512 + L * 8);
        bel[ntL][kt] = *(const f16x8*)(wsw + WS_ENC_L + tile * 512 + L * 8);
      }
    f16x8 pah[4][2], pal[4][2];
    #pragma unroll
    for (int mt = 0; mt < 4; ++mt)
      #pragma unroll
      for (int kt = 0; kt < 2; ++kt) {
        int off = (mt * 16 + c) * 72 + kt * 32 + q * 8;
        pah[mt][kt] = *(const f16x8*)(sPEh + off);
        pal[mt][kt] = *(const f16x8*)(sPEl + off);
      }
    f32x4 a1[4][2], a2[4][2];
    #pragma unroll
    for (int mt = 0; mt < 4; ++mt)
      #pragma unroll
      for (int ntL = 0; ntL < 2; ++ntL) { a1[mt][ntL] = (f32x4)0.0f; a2[mt][ntL] = (f32x4)0.0f; }
    __builtin_amdgcn_s_setprio(1);
    #pragma unroll
    for (int kt = 0; kt < 2; ++kt)
      #pragma unroll
      for (int mt = 0; mt < 4; ++mt)
        #pragma unroll
        for (int ntL = 0; ntL < 2; ++ntL) {
          a1[mt][ntL] = MFMA(pah[mt][kt], beh[ntL][kt], a1[mt][ntL]);
          a2[mt][ntL] = MFMA(pah[mt][kt], bel[ntL][kt], a2[mt][ntL]);
          a2[mt][ntL] = MFMA(pal[mt][kt], beh[ntL][kt], a2[mt][ntL]);
        }
    __builtin_amdgcn_s_setprio(0);
    __syncthreads();                                 // (2) sPE reads done -> sYl writable
    float bb0 = b_enc[(2 * w) * 16 + c];
    float bb1 = b_enc[(2 * w + 1) * 16 + c];
    #pragma unroll
    for (int mt = 0; mt < 4; ++mt)
      #pragma unroll
      for (int ntL = 0; ntL < 2; ++ntL) {
        float bb = ntL ? bb1 : bb0;
        int col = (2 * w + ntL) * 16 + c;
        #pragma unroll
        for (int r = 0; r < 4; ++r) {
          float v = fmaxf(a1[mt][ntL][r] + a2[mt][ntL][r] * INV2048 + bb, 0.0f);
          int row = mt * 16 + q * 4 + r;
          _Float16 h = (_Float16)v;
          sYh[row * 136 + col] = h;
          sYl[row * 136 + col] = (_Float16)((v - (float)h) * 2048.0f);
        }
      }
  }
  __syncthreads();                                   // (3)

  // hoist Y hi frags (64 VGPR); lo re-read from sYl per use
  f16x8 Ah[4][4];
  #pragma unroll
  for (int nt = 0; nt < 4; ++nt)
    #pragma unroll
    for (int kt = 0; kt < 4; ++kt)
      Ah[nt][kt] = *(const f16x8*)(sYh + (nt * 16 + c) * 136 + kt * 32 + q * 8);
  const f32x4 wsv0 = *(const f32x4*)(w_sig + (2 * w) * 16 + q * 4);
  const f32x4 wsv1 = *(const f32x4*)(w_sig + (2 * w + 1) * 16 + q * 4);

  // ---- pass 1: 16-step (e,i) pipeline, double-buffered weight prefetch ----
  float psum[4] = {0.f, 0.f, 0.f, 0.f};

  auto LOADW = [&](int s, f16x8 bh[4], f16x8 bl[4], f32x4& bb) {
    int e = s >> 1, i = s & 1;
    int tbase = (e * 8 + 2 * w + i) * 4;
    #pragma unroll
    for (int kt = 0; kt < 4; ++kt) {
      bh[kt] = *(const f16x8*)(wsw + WS_SH_H + (tbase + kt) * 512 + L * 8);
      bl[kt] = *(const f16x8*)(wsw + WS_SH_L + (tbase + kt) * 512 + L * 8);
    }
    bb = *(const f32x4*)(b_sh + e * 128 + (2 * w + i) * 16 + q * 4);
  };

  auto STEP = [&](int s, const f16x8 bh[4], const f16x8 bl[4], const f32x4& bb) {
    f32x4 a1[4], a2[4];
    #pragma unroll
    for (int nt = 0; nt < 4; ++nt) { a1[nt] = (f32x4)0.0f; a2[nt] = (f32x4)0.0f; }
    __builtin_amdgcn_s_setprio(1);
    #pragma unroll
    for (int kt = 0; kt < 4; ++kt)
      #pragma unroll
      for (int nt = 0; nt < 4; ++nt) {
        f16x8 al = *(const f16x8*)(sYl + (nt * 16 + c) * 136 + kt * 32 + q * 8);
        a1[nt] = MFMA(bh[kt], Ah[nt][kt], a1[nt]);
        a2[nt] = MFMA(bl[kt], Ah[nt][kt], a2[nt]);
        a2[nt] = MFMA(bh[kt], al, a2[nt]);
      }
    __builtin_amdgcn_s_setprio(0);
    f32x4 wv = (s & 1) ? wsv1 : wsv0;
    #pragma unroll
    for (int nt = 0; nt < 4; ++nt)
      #pragma unroll
      for (int r = 0; r < 4; ++r) {
        float sv = fmaxf(fmaf(a2[nt][r], INV2048, a1[nt][r]) + bb[r], 0.0f);
        psum[nt] = fmaf(sv, wv[r], psum[nt]);
      }
    if (s & 1) {                       // end of expert e = s>>1
      int e = s >> 1;
      #pragma unroll
      for (int nt = 0; nt < 4; ++nt) {
        float v = psum[nt];
        v += __shfl_xor(v, 16);
        v += __shfl_xor(v, 32);
        if (q == 0) sRedE[e * 256 + w * 64 + nt * 16 + c] = v;
        psum[nt] = 0.f;
      }
    }
  };

  {
    f16x8 bh0[4], bl0[4], bh1[4], bl1[4];
    f32x4 bb0, bb1;
    LOADW(0, bh0, bl0, bb0);
    #pragma unroll
    for (int s = 0; s < 16; ++s) {
      if ((s & 1) == 0) {
        if (s + 1 < 16) LOADW(s + 1, bh1, bl1, bb1);
        STEP(s, bh0, bl0, bb0);
      } else {
        if (s + 1 < 16) LOADW(s + 1, bh0, bl0, bb0);
        STEP(s, bh1, bl1, bb1);
      }
    }
  }
  __syncthreads();                                   // (4) — only pass-1 barrier

  // ---- argmax: distributed, 4 threads/point x 2 experts, gumbel inline ----
  {
    int pt = t >> 2;
    int eb = (t & 3) * 2;
    float best = -1e30f, bsig = 0.0f;
    int bide = 0;
    const float bs = b_sig[0];
    #pragma unroll
    for (int j = 0; j < 2; ++j) {
      int e = eb + j;
      const float* rp = sRedE + e * 256 + pt;
      float s = (rp[0] + rp[64]) + (rp[128] + rp[192]);
      float dotv = s + bs;
      float sig = fmaxf(dotv, 0.0f) + log1pf(expf(-fabsf(dotv)));
      float z = logf(sig + 1e-10f) / 0.166667f;
      float score = z + gumbel_for((unsigned)((n0 + pt) * 8 + e));
      if (score > best) { best = score; bsig = sig; bide = e; }
    }
    #pragma unroll
    for (int m = 1; m <= 2; m <<= 1) {
      float oS  = __shfl_xor(best, m);
      float oSg = __shfl_xor(bsig, m);
      int   oI  = __shfl_xor(bide, m);
      if (oS > best || (oS == best && oI < bide)) { best = oS; bsig = oSg; bide = oI; }
    }
    if ((t & 3) == 0) {
      S_BID(pt) = bide;                // row-pad slot; sYl dead, sSB not yet
      out[(size_t)(n0 + pt) * 4 + 3] = bsig;
    }
  }
  __syncthreads();                                   // (5)

  // ---- bucket lists: wave-0 ballot build (replaces two serial t<8 scans) ----
  if (t < 64) {
    int bid = S_BID(t);
    unsigned long long below = t ? ((~0ULL) >> (64 - t)) : 0ULL;
    int off = 0;
    #pragma unroll
    for (int e = 0; e < 8; ++e) {
      unsigned long long m = __ballot(bid == e);
      int cnt = __popcll(m);
      if (t == e) { S_CNT(e) = cnt; S_OFF(e) = off; }
      if (bid == e) {
        int rank = __popcll(m & below);
        S_LIST(off + rank) = t;
      }
      off += cnt;
    }
  }
  __syncthreads();                                   // (6)

  // ---- pass 2a: viewdir PE into sSB + winner S recompute (transposed) ----
  for (int idx = t; idx < PT * 32; idx += NTH) {
    int s = idx >> 5, cc = idx & 31;
    int pt = S_LIST(s);
    const float* xr = x + (size_t)(n0 + pt) * 6 + 3;
    float v;
    if (cc < 3)       v = xr[cc];
    else if (cc < 15) { int g = cc - 3;  v = sinf(xr[g % 3] * (float)(1 << (g / 3))); }
    else if (cc < 27) { int g = cc - 15; v = cosf(xr[g % 3] * (float)(1 << (g / 3))); }
    else              v = 0.0f;
    sSB[s * 168 + 128 + cc] = (_Float16)v;
  }
  #pragma unroll 1
  for (int ei = 0; ei < 2; ++ei) {
    int e = 2 * w + ei;
    int cnt = S_CNT(e), off = S_OFF(e);
    for (int base = 0; base < cnt; base += 16) {
      int sidx = base + c; if (sidx >= cnt) sidx = cnt - 1;
      int pt = S_LIST(off + sidx);
      f16x8 yb[4];
      #pragma unroll
      for (int kt = 0; kt < 4; ++kt)
        yb[kt] = *(const f16x8*)(sYh + pt * 136 + kt * 32 + q * 8);
      f32x4 acc[8];
      #pragma unroll
      for (int jt = 0; jt < 8; ++jt) acc[jt] = (f32x4)0.0f;
      __builtin_amdgcn_s_setprio(1);
      #pragma unroll
      for (int jt = 0; jt < 8; ++jt)
        #pragma unroll
        for (int kt = 0; kt < 4; ++kt) {
          f16x8 a = *(const f16x8*)(wsw + WS_SH_H + ((e * 8 + jt) * 4 + kt) * 512 + L * 8);
          acc[jt] = MFMA(a, yb[kt], acc[jt]);
        }
      __builtin_amdgcn_s_setprio(0);
      bool wr = (base + c) < cnt;
      int slot = off + base + c;
      #pragma unroll
      for (int jt = 0; jt < 8; ++jt) {
        f32x4 bb = *(const f32x4*)(b_sh + e * 128 + jt * 16 + q * 4);
        f16x4 v;
        #pragma unroll
        for (int r = 0; r < 4; ++r)
          v[r] = (_Float16)fmaxf(acc[jt][r] + bb[r], 0.0f);
        if (wr) *(f16x4*)(sSB + slot * 168 + jt * 16 + q * 4) = v;
      }
    }
  }
  __syncthreads();                                   // (7) sYh dead -> sH writable

  // ---- pass 2b: rgb layer 1 via MFMA ([S;vd] @ W_r1) ----
  #pragma unroll 1
  for (int ei = 0; ei < 2; ++ei) {
    int e = 2 * w + ei;
    int cnt = S_CNT(e), off = S_OFF(e);
    for (int base = 0; base < cnt; base += 16) {
      int sidx = base + c; if (sidx >= cnt) sidx = cnt - 1;
      int slot = off + sidx;
      f16x8 ag[5];
      #pragma unroll
      for (int kt = 0; kt < 5; ++kt)
        ag[kt] = *(const f16x8*)(sSB + slot * 168 + kt * 32 + q * 8);
      f32x4 hacc[4];
      #pragma unroll
      for (int nt = 0; nt < 4; ++nt) hacc[nt] = (f32x4)0.0f;
      __builtin_amdgcn_s_setprio(1);
      #pragma unroll
      for (int nt = 0; nt < 4; ++nt)
        #pragma unroll
        for (int kt = 0; kt < 5; ++kt) {
          f16x8 bf = *(const f16x8*)(wsw + WS_R1_H + ((e * 4 + nt) * 5 + kt) * 512 + L * 8);
          hacc[nt] = MFMA(ag[kt], bf, hacc[nt]);
        }
      __builtin_amdgcn_s_setprio(0);
      #pragma unroll
      for (int nt = 0; nt < 4; ++nt) {
        float bb = b_r1[e * 64 + nt * 16 + c];
        #pragma unroll
        for (int r = 0; r < 4; ++r) {
          int m = q * 4 + r;
          if (base + m < cnt)
            sH[(off + base + m) * 68 + nt * 16 + c] = fmaxf(hacc[nt][r] + bb, 0.0f);
        }
      }
    }
  }
  __syncthreads();                                   // (8)

  // ---- layer 2: rgb = sigmoid(h @ W_r2 + b) ----
  if (t < 192) {
    int s = t / 3, o = t - s * 3;
    int pt = S_LIST(s);
    int e = S_BID(pt);
    float a = b_r2[e * 3 + o];
    const float* w2 = W_r2 + e * 192 + o;
    #pragma unroll
    for (int jj = 0; jj < 64; jj += 4) {
      f32x4 h4 = *(const f32x4*)(sH + s * 68 + jj);
      a = fmaf(h4.x, w2[jj * 3], a);
      a = fmaf(h4.y, w2[jj * 3 + 3], a);
      a = fmaf(h4.z, w2[jj * 3 + 6], a);
      a = fmaf(h4.w, w2[jj * 3 + 9], a);
    }
    out[(size_t)(n0 + pt) * 4 + o] = 1.0f / (1.0f + expf(-a));
  }
}

extern "C" void kernel_launch(void* const* d_in, const int* in_sizes, int n_in,
                              void* d_out, int out_size, void* d_ws, size_t ws_size,
                              hipStream_t stream) {
  (void)in_sizes; (void)n_in; (void)ws_size; (void)out_size;
  const float* x     = (const float*)d_in[0];
  const float* W_enc = (const float*)d_in[1];
  const float* b_enc = (const float*)d_in[2];
  const float* W_sh  = (const float*)d_in[3];
  const float* b_sh  = (const float*)d_in[4];
  const float* w_sig = (const float*)d_in[5];
  const float* b_sig = (const float*)d_in[6];
  const float* W_r1  = (const float*)d_in[7];
  const float* b_r1  = (const float*)d_in[8];
  const float* W_r2  = (const float*)d_in[9];
  const float* b_r2  = (const float*)d_in[10];
  _Float16* ws = (_Float16*)d_ws;     // needs 720896 B
  float* outp = (float*)d_out;
  prep_kernel<<<864, 256, 0, stream>>>(W_enc, W_sh, W_r1, ws);
  nerf_moe_kernel<<<NBLK, NTH, 0, stream>>>(x, b_enc, b_sh, w_sig, b_sig,
                                            b_r1, W_r2, b_r2, ws, outp);
}

// Round 8
// 259.546 us; speedup vs baseline: 2.0554x; 1.0052x over previous
//
#include <hip/hip_runtime.h>
#include <hip/hip_bf16.h>

// ---------------------------------------------------------------------------
// GumbelNeRF fused kernel, round 14: R13 champion + Al[4][2] hoist.
//
// R13 post-mortem: setprio + ballot = WIN (235 -> 212-220us dispatch,
// MfmaUtil 22 -> 25.3). Occupancy fixed at 2 blocks/CU (R8-R12 proved 3
// unreachable without spills/serialization).
// Remaining bottleneck arithmetic: pass-1 re-reads sYl 16x b128/step
// (256 reads/wave, ~8K cyc/CU of LDS issue ~ comparable to the 9K cyc of
// MFMA work). Reg budget at 2 waves/SIMD = 256; current peak ~192
// (128 VGPR + 64 AGPR) -> 64 headroom. Hoist HALF of Al (Al[4][2], +32
// VGPR): pass-1 LDS reads 16 -> 8 per step. Full hoist + dbuf would hit
// 256 exactly = spill roulette (R8 lesson).
// Sigma numerics unchanged: f16 3-product split (hi + lo/2048), fp32
// accumulate, threefry gumbel.
// ---------------------------------------------------------------------------

#define NPTS 131072
#define PT 64
#define NTH 256
#define NBLK (NPTS / PT)
#define INV2048 (1.0f / 2048.0f)

// ws sections (f16 element offsets) — identical to rounds 2-13
#define WS_ENC_H 0
#define WS_ENC_L 8192
#define WS_SH_H  16384
#define WS_SH_L  147456
#define WS_R1_H  278528

// LDS byte offsets, total 47104
#define OFF_YH   0      // sYh [64][136] f16 = 17408 ; pass2b+: sH [64][68] f32
#define OFF_B    17408  // 21504 B: sPEh[64][72](9216)+sPEl(9216) | sYl[64][136] | sSB[64][168] f16
#define OFF_RED  38912  // sRedE [8][4][64] f32 = 8192
#define SMEM_SZ  47104

// smalls live in sSB row-pad (cols 160..167 = bytes 320..335 of each 336B row)
#define S_LIST(s) (*(int*)(smem + OFF_B + (s) * 336 + 320))
#define S_BID(p)  (*(int*)(smem + OFF_B + (p) * 336 + 324))
#define S_CNT(e)  (*(int*)(smem + OFF_B + (e) * 336 + 328))
#define S_OFF(e)  (*(int*)(smem + OFF_B + (e) * 336 + 332))

typedef __attribute__((ext_vector_type(8))) _Float16 f16x8;
typedef __attribute__((ext_vector_type(4))) _Float16 f16x4;
typedef __attribute__((ext_vector_type(4))) float f32x4;

#define MFMA(a, b, c) __builtin_amdgcn_mfma_f32_16x16x32_f16((a), (b), (c), 0, 0, 0)

__device__ __forceinline__ unsigned rotl32(unsigned x, int d) {
  return (x << d) | (x >> (32 - d));
}

// JAX threefry2x32, keys (0,42), counter (0, flat), partitionable fold.
__device__ __forceinline__ float gumbel_for(unsigned flat) {
  const unsigned k0 = 0u, k1 = 42u;
  const unsigned ks2 = k0 ^ k1 ^ 0x1BD11BDAu;
  unsigned x0 = 0u + k0;
  unsigned x1 = flat + k1;
#define TF_RND(r) { x0 += x1; x1 = rotl32(x1, r); x1 ^= x0; }
  TF_RND(13) TF_RND(15) TF_RND(26) TF_RND(6)
  x0 += k1;  x1 += ks2 + 1u;
  TF_RND(17) TF_RND(29) TF_RND(16) TF_RND(24)
  x0 += ks2; x1 += k0 + 2u;
  TF_RND(13) TF_RND(15) TF_RND(26) TF_RND(6)
  x0 += k0;  x1 += k1 + 3u;
  TF_RND(17) TF_RND(29) TF_RND(16) TF_RND(24)
  x0 += k1;  x1 += ks2 + 4u;
  TF_RND(13) TF_RND(15) TF_RND(26) TF_RND(6)
  x0 += ks2; x1 += k0 + 5u;
#undef TF_RND
  unsigned bits = x0 ^ x1;
  float u = __uint_as_float((bits >> 9) | 0x3f800000u) - 1.0f;
  return -logf(-logf(u + 1e-20f) + 1e-20f);
}

// ---------------------------------------------------------------------------
// prep: fp32 weights -> fragment-linear f16 (scaled split) in ws  [unchanged]
// ---------------------------------------------------------------------------
__global__ void prep_kernel(const float* __restrict__ W_enc,
                            const float* __restrict__ W_sh,
                            const float* __restrict__ W_r1,
                            _Float16* __restrict__ ws) {
  int idx = blockIdx.x * 256 + threadIdx.x;
  if (idx < 8192) {
    int tile = idx >> 9, r = idx & 511;
    int L = r >> 3, j = r & 7;
    int nt = tile >> 1, kt = tile & 1;
    int k = kt * 32 + (L >> 4) * 8 + j;
    int n = nt * 16 + (L & 15);
    float v = (k < 63) ? W_enc[k * 128 + n] : 0.0f;
    _Float16 h = (_Float16)v;
    ws[WS_ENC_H + idx] = h;
    ws[WS_ENC_L + idx] = (_Float16)((v - (float)h) * 2048.0f);
  } else if (idx < 8192 + 131072) {
    int s = idx - 8192;
    int tile = s >> 9, r = s & 511;
    int L = r >> 3, j = r & 7;
    int e = tile >> 5, nt = (tile >> 2) & 7, kt = tile & 3;
    int k = kt * 32 + (L >> 4) * 8 + j;
    int n = nt * 16 + (L & 15);
    float v = W_sh[e * 16384 + k * 128 + n];
    _Float16 h = (_Float16)v;
    ws[WS_SH_H + s] = h;
    ws[WS_SH_L + s] = (_Float16)((v - (float)h) * 2048.0f);
  } else if (idx < 8192 + 131072 + 81920) {
    int s = idx - (8192 + 131072);
    int tile = s >> 9, r = s & 511;
    int L = r >> 3, j = r & 7;
    int e = tile / 20, rr = tile % 20;
    int nt = rr / 5, kt = rr % 5;
    int k = kt * 32 + (L >> 4) * 8 + j;
    int n = nt * 16 + (L & 15);
    float v = (k < 155) ? W_r1[e * 9920 + k * 64 + n] : 0.0f;
    ws[WS_R1_H + s] = (_Float16)v;
  }
}

// ---------------------------------------------------------------------------
__global__ __launch_bounds__(NTH, 2)
void nerf_moe_kernel(const float* __restrict__ x,
                     const float* __restrict__ b_enc,
                     const float* __restrict__ b_sh,
                     const float* __restrict__ w_sig, const float* __restrict__ b_sig,
                     const float* __restrict__ b_r1,
                     const float* __restrict__ W_r2,  const float* __restrict__ b_r2,
                     const _Float16* __restrict__ wsw,
                     float* __restrict__ out) {
  __shared__ __align__(16) unsigned char smem[SMEM_SZ];
  _Float16* sYh  = (_Float16*)(smem + OFF_YH);
  float*    sH   = (float*)(smem + OFF_YH);
  _Float16* sYl  = (_Float16*)(smem + OFF_B);
  _Float16* sPEh = (_Float16*)(smem + OFF_B);
  _Float16* sPEl = (_Float16*)(smem + OFF_B + 9216);
  _Float16* sSB  = (_Float16*)(smem + OFF_B);
  float*    sRedE = (float*)(smem + OFF_RED);   // [8][4][64]

  const int t  = threadIdx.x;
  const int w  = t >> 6;        // wave id 0..3
  const int L  = t & 63;        // lane
  const int q  = L >> 4;        // quad 0..3
  const int c  = L & 15;
  const int n0 = blockIdx.x * PT;

  // ---- phase 0: xyz positional encoding ----
  for (int idx = t; idx < PT * 64; idx += NTH) {
    int p = idx >> 6, f = idx & 63;
    const float* xr = x + (size_t)(n0 + p) * 6;
    float v;
    if (f < 3)       v = xr[f];
    else if (f < 33) { int g = f - 3;  v = sinf(xr[g % 3] * (float)(1 << (g / 3))); }
    else if (f < 63) { int g = f - 33; v = cosf(xr[g % 3] * (float)(1 << (g / 3))); }
    else             v = 0.0f;
    _Float16 h = (_Float16)v;
    sPEh[p * 72 + f] = h;
    sPEl[p * 72 + f] = (_Float16)((v - (float)h) * 2048.0f);
  }
  __syncthreads();                                   // (1)

  // ---- phase A: Y = relu(PE @ W_enc + b) via MFMA ----
  {
    f16x8 beh[2][2], bel[2][2];
    #pragma unroll
    for (int ntL = 0; ntL < 2; ++ntL)
      #pragma unroll
      for (int kt = 0; kt < 2; ++kt) {
        int tile = (2 * w + ntL) * 2 + kt;
        beh[ntL][kt] = *(const f16x8*)(wsw + WS_ENC_H + tile * 512 + L * 8);
        bel[ntL][kt] = *(const f16x8*)(wsw + WS_ENC_L + tile * 512 + L * 8);
      }
    f16x8 pah[4][2], pal[4][2];
    #pragma unroll
    for (int mt = 0; mt < 4; ++mt)
      #pragma unroll
      for (int kt = 0; kt < 2; ++kt) {
        int off = (mt * 16 + c) * 72 + kt * 32 + q * 8;
        pah[mt][kt] = *(const f16x8*)(sPEh + off);
        pal[mt][kt] = *(const f16x8*)(sPEl + off);
      }
    f32x4 a1[4][2], a2[4][2];
    #pragma unroll
    for (int mt = 0; mt < 4; ++mt)
      #pragma unroll
      for (int ntL = 0; ntL < 2; ++ntL) { a1[mt][ntL] = (f32x4)0.0f; a2[mt][ntL] = (f32x4)0.0f; }
    __builtin_amdgcn_s_setprio(1);
    #pragma unroll
    for (int kt = 0; kt < 2; ++kt)
      #pragma unroll
      for (int mt = 0; mt < 4; ++mt)
        #pragma unroll
        for (int ntL = 0; ntL < 2; ++ntL) {
          a1[mt][ntL] = MFMA(pah[mt][kt], beh[ntL][kt], a1[mt][ntL]);
          a2[mt][ntL] = MFMA(pah[mt][kt], bel[ntL][kt], a2[mt][ntL]);
          a2[mt][ntL] = MFMA(pal[mt][kt], beh[ntL][kt], a2[mt][ntL]);
        }
    __builtin_amdgcn_s_setprio(0);
    __syncthreads();                                 // (2) sPE reads done -> sYl writable
    float bb0 = b_enc[(2 * w) * 16 + c];
    float bb1 = b_enc[(2 * w + 1) * 16 + c];
    #pragma unroll
    for (int mt = 0; mt < 4; ++mt)
      #pragma unroll
      for (int ntL = 0; ntL < 2; ++ntL) {
        float bb = ntL ? bb1 : bb0;
        int col = (2 * w + ntL) * 16 + c;
        #pragma unroll
        for (int r = 0; r < 4; ++r) {
          float v = fmaxf(a1[mt][ntL][r] + a2[mt][ntL][r] * INV2048 + bb, 0.0f);
          int row = mt * 16 + q * 4 + r;
          _Float16 h = (_Float16)v;
          sYh[row * 136 + col] = h;
          sYl[row * 136 + col] = (_Float16)((v - (float)h) * 2048.0f);
        }
      }
  }
  __syncthreads();                                   // (3)

  // hoist Y hi frags (64 VGPR) + lo frags for kt=0..1 (32 VGPR);
  // lo kt=2..3 re-read from sYl per use (8 b128/step instead of 16)
  f16x8 Ah[4][4];
  #pragma unroll
  for (int nt = 0; nt < 4; ++nt)
    #pragma unroll
    for (int kt = 0; kt < 4; ++kt)
      Ah[nt][kt] = *(const f16x8*)(sYh + (nt * 16 + c) * 136 + kt * 32 + q * 8);
  f16x8 Al[4][2];
  #pragma unroll
  for (int nt = 0; nt < 4; ++nt)
    #pragma unroll
    for (int kt = 0; kt < 2; ++kt)
      Al[nt][kt] = *(const f16x8*)(sYl + (nt * 16 + c) * 136 + kt * 32 + q * 8);
  const f32x4 wsv0 = *(const f32x4*)(w_sig + (2 * w) * 16 + q * 4);
  const f32x4 wsv1 = *(const f32x4*)(w_sig + (2 * w + 1) * 16 + q * 4);

  // ---- pass 1: 16-step (e,i) pipeline, double-buffered weight prefetch ----
  float psum[4] = {0.f, 0.f, 0.f, 0.f};

  auto LOADW = [&](int s, f16x8 bh[4], f16x8 bl[4], f32x4& bb) {
    int e = s >> 1, i = s & 1;
    int tbase = (e * 8 + 2 * w + i) * 4;
    #pragma unroll
    for (int kt = 0; kt < 4; ++kt) {
      bh[kt] = *(const f16x8*)(wsw + WS_SH_H + (tbase + kt) * 512 + L * 8);
      bl[kt] = *(const f16x8*)(wsw + WS_SH_L + (tbase + kt) * 512 + L * 8);
    }
    bb = *(const f32x4*)(b_sh + e * 128 + (2 * w + i) * 16 + q * 4);
  };

  auto STEP = [&](int s, const f16x8 bh[4], const f16x8 bl[4], const f32x4& bb) {
    f32x4 a1[4], a2[4];
    #pragma unroll
    for (int nt = 0; nt < 4; ++nt) { a1[nt] = (f32x4)0.0f; a2[nt] = (f32x4)0.0f; }
    __builtin_amdgcn_s_setprio(1);
    #pragma unroll
    for (int kt = 0; kt < 4; ++kt)
      #pragma unroll
      for (int nt = 0; nt < 4; ++nt) {
        f16x8 al;
        if (kt < 2) al = Al[nt][kt];
        else        al = *(const f16x8*)(sYl + (nt * 16 + c) * 136 + kt * 32 + q * 8);
        a1[nt] = MFMA(bh[kt], Ah[nt][kt], a1[nt]);
        a2[nt] = MFMA(bl[kt], Ah[nt][kt], a2[nt]);
        a2[nt] = MFMA(bh[kt], al, a2[nt]);
      }
    __builtin_amdgcn_s_setprio(0);
    f32x4 wv = (s & 1) ? wsv1 : wsv0;
    #pragma unroll
    for (int nt = 0; nt < 4; ++nt)
      #pragma unroll
      for (int r = 0; r < 4; ++r) {
        float sv = fmaxf(fmaf(a2[nt][r], INV2048, a1[nt][r]) + bb[r], 0.0f);
        psum[nt] = fmaf(sv, wv[r], psum[nt]);
      }
    if (s & 1) {                       // end of expert e = s>>1
      int e = s >> 1;
      #pragma unroll
      for (int nt = 0; nt < 4; ++nt) {
        float v = psum[nt];
        v += __shfl_xor(v, 16);
        v += __shfl_xor(v, 32);
        if (q == 0) sRedE[e * 256 + w * 64 + nt * 16 + c] = v;
        psum[nt] = 0.f;
      }
    }
  };

  {
    f16x8 bh0[4], bl0[4], bh1[4], bl1[4];
    f32x4 bb0, bb1;
    LOADW(0, bh0, bl0, bb0);
    #pragma unroll
    for (int s = 0; s < 16; ++s) {
      if ((s & 1) == 0) {
        if (s + 1 < 16) LOADW(s + 1, bh1, bl1, bb1);
        STEP(s, bh0, bl0, bb0);
      } else {
        if (s + 1 < 16) LOADW(s + 1, bh0, bl0, bb0);
        STEP(s, bh1, bl1, bb1);
      }
    }
  }
  __syncthreads();                                   // (4) — only pass-1 barrier

  // ---- argmax: distributed, 4 threads/point x 2 experts, gumbel inline ----
  {
    int pt = t >> 2;
    int eb = (t & 3) * 2;
    float best = -1e30f, bsig = 0.0f;
    int bide = 0;
    const float bs = b_sig[0];
    #pragma unroll
    for (int j = 0; j < 2; ++j) {
      int e = eb + j;
      const float* rp = sRedE + e * 256 + pt;
      float s = (rp[0] + rp[64]) + (rp[128] + rp[192]);
      float dotv = s + bs;
      float sig = fmaxf(dotv, 0.0f) + log1pf(expf(-fabsf(dotv)));
      float z = logf(sig + 1e-10f) / 0.166667f;
      float score = z + gumbel_for((unsigned)((n0 + pt) * 8 + e));
      if (score > best) { best = score; bsig = sig; bide = e; }
    }
    #pragma unroll
    for (int m = 1; m <= 2; m <<= 1) {
      float oS  = __shfl_xor(best, m);
      float oSg = __shfl_xor(bsig, m);
      int   oI  = __shfl_xor(bide, m);
      if (oS > best || (oS == best && oI < bide)) { best = oS; bsig = oSg; bide = oI; }
    }
    if ((t & 3) == 0) {
      S_BID(pt) = bide;                // row-pad slot; sYl dead, sSB not yet
      out[(size_t)(n0 + pt) * 4 + 3] = bsig;
    }
  }
  __syncthreads();                                   // (5)

  // ---- bucket lists: wave-0 ballot build (replaces two serial t<8 scans) ----
  if (t < 64) {
    int bid = S_BID(t);
    unsigned long long below = t ? ((~0ULL) >> (64 - t)) : 0ULL;
    int off = 0;
    #pragma unroll
    for (int e = 0; e < 8; ++e) {
      unsigned long long m = __ballot(bid == e);
      int cnt = __popcll(m);
      if (t == e) { S_CNT(e) = cnt; S_OFF(e) = off; }
      if (bid == e) {
        int rank = __popcll(m & below);
        S_LIST(off + rank) = t;
      }
      off += cnt;
    }
  }
  __syncthreads();                                   // (6)

  // ---- pass 2a: viewdir PE into sSB + winner S recompute (transposed) ----
  for (int idx = t; idx < PT * 32; idx += NTH) {
    int s = idx >> 5, cc = idx & 31;
    int pt = S_LIST(s);
    const float* xr = x + (size_t)(n0 + pt) * 6 + 3;
    float v;
    if (cc < 3)       v = xr[cc];
    else if (cc < 15) { int g = cc - 3;  v = sinf(xr[g % 3] * (float)(1 << (g / 3))); }
    else if (cc < 27) { int g = cc - 15; v = cosf(xr[g % 3] * (float)(1 << (g / 3))); }
    else              v = 0.0f;
    sSB[s * 168 + 128 + cc] = (_Float16)v;
  }
  #pragma unroll 1
  for (int ei = 0; ei < 2; ++ei) {
    int e = 2 * w + ei;
    int cnt = S_CNT(e), off = S_OFF(e);
    for (int base = 0; base < cnt; base += 16) {
      int sidx = base + c; if (sidx >= cnt) sidx = cnt - 1;
      int pt = S_LIST(off + sidx);
      f16x8 yb[4];
      #pragma unroll
      for (int kt = 0; kt < 4; ++kt)
        yb[kt] = *(const f16x8*)(sYh + pt * 136 + kt * 32 + q * 8);
      f32x4 acc[8];
      #pragma unroll
      for (int jt = 0; jt < 8; ++jt) acc[jt] = (f32x4)0.0f;
      __builtin_amdgcn_s_setprio(1);
      #pragma unroll
      for (int jt = 0; jt < 8; ++jt)
        #pragma unroll
        for (int kt = 0; kt < 4; ++kt) {
          f16x8 a = *(const f16x8*)(wsw + WS_SH_H + ((e * 8 + jt) * 4 + kt) * 512 + L * 8);
          acc[jt] = MFMA(a, yb[kt], acc[jt]);
        }
      __builtin_amdgcn_s_setprio(0);
      bool wr = (base + c) < cnt;
      int slot = off + base + c;
      #pragma unroll
      for (int jt = 0; jt < 8; ++jt) {
        f32x4 bb = *(const f32x4*)(b_sh + e * 128 + jt * 16 + q * 4);
        f16x4 v;
        #pragma unroll
        for (int r = 0; r < 4; ++r)
          v[r] = (_Float16)fmaxf(acc[jt][r] + bb[r], 0.0f);
        if (wr) *(f16x4*)(sSB + slot * 168 + jt * 16 + q * 4) = v;
      }
    }
  }
  __syncthreads();                                   // (7) sYh dead -> sH writable

  // ---- pass 2b: rgb layer 1 via MFMA ([S;vd] @ W_r1) ----
  #pragma unroll 1
  for (int ei = 0; ei < 2; ++ei) {
    int e = 2 * w + ei;
    int cnt = S_CNT(e), off = S_OFF(e);
    for (int base = 0; base < cnt; base += 16) {
      int sidx = base + c; if (sidx >= cnt) sidx = cnt - 1;
      int slot = off + sidx;
      f16x8 ag[5];
      #pragma unroll
      for (int kt = 0; kt < 5; ++kt)
        ag[kt] = *(const f16x8*)(sSB + slot * 168 + kt * 32 + q * 8);
      f32x4 hacc[4];
      #pragma unroll
      for (int nt = 0; nt < 4; ++nt) hacc[nt] = (f32x4)0.0f;
      __builtin_amdgcn_s_setprio(1);
      #pragma unroll
      for (int nt = 0; nt < 4; ++nt)
        #pragma unroll
        for (int kt = 0; kt < 5; ++kt) {
          f16x8 bf = *(const f16x8*)(wsw + WS_R1_H + ((e * 4 + nt) * 5 + kt) * 512 + L * 8);
          hacc[nt] = MFMA(ag[kt], bf, hacc[nt]);
        }
      __builtin_amdgcn_s_setprio(0);
      #pragma unroll
      for (int nt = 0; nt < 4; ++nt) {
        float bb = b_r1[e * 64 + nt * 16 + c];
        #pragma unroll
        for (int r = 0; r < 4; ++r) {
          int m = q * 4 + r;
          if (base + m < cnt)
            sH[(off + base + m) * 68 + nt * 16 + c] = fmaxf(hacc[nt][r] + bb, 0.0f);
        }
      }
    }
  }
  __syncthreads();                                   // (8)

  // ---- layer 2: rgb = sigmoid(h @ W_r2 + b) ----
  if (t < 192) {
    int s = t / 3, o = t - s * 3;
    int pt = S_LIST(s);
    int e = S_BID(pt);
    float a = b_r2[e * 3 + o];
    const float* w2 = W_r2 + e * 192 + o;
    #pragma unroll
    for (int jj = 0; jj < 64; jj += 4) {
      f32x4 h4 = *(const f32x4*)(sH + s * 68 + jj);
      a = fmaf(h4.x, w2[jj * 3], a);
      a = fmaf(h4.y, w2[jj * 3 + 3], a);
      a = fmaf(h4.z, w2[jj * 3 + 6], a);
      a = fmaf(h4.w, w2[jj * 3 + 9], a);
    }
    out[(size_t)(n0 + pt) * 4 + o] = 1.0f / (1.0f + expf(-a));
  }
}

extern "C" void kernel_launch(void* const* d_in, const int* in_sizes, int n_in,
                              void* d_out, int out_size, void* d_ws, size_t ws_size,
                              hipStream_t stream) {
  (void)in_sizes; (void)n_in; (void)ws_size; (void)out_size;
  const float* x     = (const float*)d_in[0];
  const float* W_enc = (const float*)d_in[1];
  const float* b_enc = (const float*)d_in[2];
  const float* W_sh  = (const float*)d_in[3];
  const float* b_sh  = (const float*)d_in[4];
  const float* w_sig = (const float*)d_in[5];
  const float* b_sig = (const float*)d_in[6];
  const float* W_r1  = (const float*)d_in[7];
  const float* b_r1  = (const float*)d_in[8];
  const float* W_r2  = (const float*)d_in[9];
  const float* b_r2  = (const float*)d_in[10];
  _Float16* ws = (_Float16*)d_ws;     // needs 720896 B
  float* outp = (float*)d_out;
  prep_kernel<<<864, 256, 0, stream>>>(W_enc, W_sh, W_r1, ws);
  nerf_moe_kernel<<<NBLK, NTH, 0, stream>>>(x, b_enc, b_sh, w_sig, b_sig,
                                            b_r1, W_r2, b_r2, ws, outp);
}

// Round 10
// 256.106 us; speedup vs baseline: 2.0830x; 1.0134x over previous
//
#include <hip/hip_runtime.h>
#include <hip/hip_bf16.h>

// ---------------------------------------------------------------------------
// GumbelNeRF fused kernel, round 15b (resubmit after infra failure; source
// identical to R15): R12's register splits + CORRECT strides + 3 blocks/CU
// + R13's setprio/ballot.
//
// R14 post-mortem: Al hoist neutral -> pass-1 LDS not critical path. Cycle
// model: ~900 MFMA/wave x 19.4 cyc/SIMD-MFMA x 8 waves = 140K cyc vs 509K
// wall = 27% (matches MfmaUtil 25) -> 3.6x headroom, all stall; only TLP
// can close it. Re-audit of the occupancy arc: R12 DID kill spills at the
// 168-reg budget (FETCH 4.6MB WRITE 2MB, 84+84) - its 503us was the broken
// 276B row stride (un-aligned ds_read_b128 -> 4x LDS ops), not the splits.
// "Splits + correct strides + 3 blocks" was never tested. R15 tests it:
//  - phase A mt-halves split; pass 1 Ah[4][3] single-buffered rolled loop;
//    pass 2a jt 2x4 split; pass 2b nt 2x2 split; asm fences between halves.
//  - strides 136 (sY), 72 (sPE), 68 (sH) - all 16B-aligned rows (R7-proven).
//  - sRed[8][64] atomic reduction, LDS 40960, launch_bounds(256,3).
//  - setprio(1/0) around MFMA clusters + ballot bucket build (R13 wins).
// Decision rule: dur >= 212 => 3-block arc closes for good, R14 is champion.
// Second identical infra failure => revert to R14 next round.
// Sigma numerics unchanged: f16 3-product split (hi + lo/2048), fp32
// accumulate, threefry gumbel.
// ---------------------------------------------------------------------------

#define NPTS 131072
#define PT 64
#define NTH 256
#define NBLK (NPTS / PT)
#define INV2048 (1.0f / 2048.0f)

// ws sections (f16 element offsets) — identical to rounds 2-14
#define WS_ENC_H 0
#define WS_ENC_L 8192
#define WS_SH_H  16384
#define WS_SH_L  147456
#define WS_R1_H  278528

// LDS byte offsets, total 40960 (R8 layout, proven correct)
#define OFF_YH   0      // sYh [64][136] f16 = 17408 ; pass2b+: sH [64][68] f32
#define OFF_B    17408  // 21504 B: sPEh[64][72](9216)+sPEl(9216) | sYl[64][136] | sSB[64][168] f16
#define OFF_RED  38912  // sRed [8][64] f32 = 2048 (atomic cross-wave sum)
#define SMEM_SZ  40960

// smalls live in sSB row-pad (cols 160..167 = bytes 320..335 of each 336B row)
#define S_LIST(s) (*(int*)(smem + OFF_B + (s) * 336 + 320))
#define S_BID(p)  (*(int*)(smem + OFF_B + (p) * 336 + 324))
#define S_CNT(e)  (*(int*)(smem + OFF_B + (e) * 336 + 328))
#define S_OFF(e)  (*(int*)(smem + OFF_B + (e) * 336 + 332))

typedef __attribute__((ext_vector_type(8))) _Float16 f16x8;
typedef __attribute__((ext_vector_type(4))) _Float16 f16x4;
typedef __attribute__((ext_vector_type(4))) float f32x4;

#define MFMA(a, b, c) __builtin_amdgcn_mfma_f32_16x16x32_f16((a), (b), (c), 0, 0, 0)

__device__ __forceinline__ unsigned rotl32(unsigned x, int d) {
  return (x << d) | (x >> (32 - d));
}

// JAX threefry2x32, keys (0,42), counter (0, flat), partitionable fold.
__device__ __forceinline__ float gumbel_for(unsigned flat) {
  const unsigned k0 = 0u, k1 = 42u;
  const unsigned ks2 = k0 ^ k1 ^ 0x1BD11BDAu;
  unsigned x0 = 0u + k0;
  unsigned x1 = flat + k1;
#define TF_RND(r) { x0 += x1; x1 = rotl32(x1, r); x1 ^= x0; }
  TF_RND(13) TF_RND(15) TF_RND(26) TF_RND(6)
  x0 += k1;  x1 += ks2 + 1u;
  TF_RND(17) TF_RND(29) TF_RND(16) TF_RND(24)
  x0 += ks2; x1 += k0 + 2u;
  TF_RND(13) TF_RND(15) TF_RND(26) TF_RND(6)
  x0 += k0;  x1 += k1 + 3u;
  TF_RND(17) TF_RND(29) TF_RND(16) TF_RND(24)
  x0 += k1;  x1 += ks2 + 4u;
  TF_RND(13) TF_RND(15) TF_RND(26) TF_RND(6)
  x0 += ks2; x1 += k0 + 5u;
#undef TF_RND
  unsigned bits = x0 ^ x1;
  float u = __uint_as_float((bits >> 9) | 0x3f800000u) - 1.0f;
  return -logf(-logf(u + 1e-20f) + 1e-20f);
}

// ---------------------------------------------------------------------------
// prep: fp32 weights -> fragment-linear f16 (scaled split) in ws  [unchanged]
// ---------------------------------------------------------------------------
__global__ void prep_kernel(const float* __restrict__ W_enc,
                            const float* __restrict__ W_sh,
                            const float* __restrict__ W_r1,
                            _Float16* __restrict__ ws) {
  int idx = blockIdx.x * 256 + threadIdx.x;
  if (idx < 8192) {
    int tile = idx >> 9, r = idx & 511;
    int L = r >> 3, j = r & 7;
    int nt = tile >> 1, kt = tile & 1;
    int k = kt * 32 + (L >> 4) * 8 + j;
    int n = nt * 16 + (L & 15);
    float v = (k < 63) ? W_enc[k * 128 + n] : 0.0f;
    _Float16 h = (_Float16)v;
    ws[WS_ENC_H + idx] = h;
    ws[WS_ENC_L + idx] = (_Float16)((v - (float)h) * 2048.0f);
  } else if (idx < 8192 + 131072) {
    int s = idx - 8192;
    int tile = s >> 9, r = s & 511;
    int L = r >> 3, j = r & 7;
    int e = tile >> 5, nt = (tile >> 2) & 7, kt = tile & 3;
    int k = kt * 32 + (L >> 4) * 8 + j;
    int n = nt * 16 + (L & 15);
    float v = W_sh[e * 16384 + k * 128 + n];
    _Float16 h = (_Float16)v;
    ws[WS_SH_H + s] = h;
    ws[WS_SH_L + s] = (_Float16)((v - (float)h) * 2048.0f);
  } else if (idx < 8192 + 131072 + 81920) {
    int s = idx - (8192 + 131072);
    int tile = s >> 9, r = s & 511;
    int L = r >> 3, j = r & 7;
    int e = tile / 20, rr = tile % 20;
    int nt = rr / 5, kt = rr % 5;
    int k = kt * 32 + (L >> 4) * 8 + j;
    int n = nt * 16 + (L & 15);
    float v = (k < 155) ? W_r1[e * 9920 + k * 64 + n] : 0.0f;
    ws[WS_R1_H + s] = (_Float16)v;
  }
}

// ---------------------------------------------------------------------------
__global__ __launch_bounds__(NTH, 3)
void nerf_moe_kernel(const float* __restrict__ x,
                     const float* __restrict__ b_enc,
                     const float* __restrict__ b_sh,
                     const float* __restrict__ w_sig, const float* __restrict__ b_sig,
                     const float* __restrict__ b_r1,
                     const float* __restrict__ W_r2,  const float* __restrict__ b_r2,
                     const _Float16* __restrict__ wsw,
                     float* __restrict__ out) {
  __shared__ __align__(16) unsigned char smem[SMEM_SZ];
  _Float16* sYh  = (_Float16*)(smem + OFF_YH);
  float*    sH   = (float*)(smem + OFF_YH);
  _Float16* sYl  = (_Float16*)(smem + OFF_B);
  _Float16* sPEh = (_Float16*)(smem + OFF_B);
  _Float16* sPEl = (_Float16*)(smem + OFF_B + 9216);
  _Float16* sSB  = (_Float16*)(smem + OFF_B);
  float*    sRed = (float*)(smem + OFF_RED);    // [8][64] atomic

  const int t  = threadIdx.x;
  const int w  = t >> 6;        // wave id 0..3
  const int L  = t & 63;        // lane
  const int q  = L >> 4;        // quad 0..3
  const int c  = L & 15;
  const int n0 = blockIdx.x * PT;

  // zero the atomic sigma-reduction buffer (ordered vs pass 1 by barriers 1-3)
  sRed[t] = 0.0f;
  sRed[t + 256] = 0.0f;

  // ---- phase 0: xyz positional encoding ----
  for (int idx = t; idx < PT * 64; idx += NTH) {
    int p = idx >> 6, f = idx & 63;
    const float* xr = x + (size_t)(n0 + p) * 6;
    float v;
    if (f < 3)       v = xr[f];
    else if (f < 33) { int g = f - 3;  v = sinf(xr[g % 3] * (float)(1 << (g / 3))); }
    else if (f < 63) { int g = f - 33; v = cosf(xr[g % 3] * (float)(1 << (g / 3))); }
    else             v = 0.0f;
    _Float16 h = (_Float16)v;
    sPEh[p * 72 + f] = h;
    sPEl[p * 72 + f] = (_Float16)((v - (float)h) * 2048.0f);
  }
  __syncthreads();                                   // (1)

  // ---- phase A: Y = relu(PE @ W_enc + b) via MFMA, mt split in halves ----
  {
    f16x8 beh[2][2], bel[2][2];
    #pragma unroll
    for (int ntL = 0; ntL < 2; ++ntL)
      #pragma unroll
      for (int kt = 0; kt < 2; ++kt) {
        int tile = (2 * w + ntL) * 2 + kt;
        beh[ntL][kt] = *(const f16x8*)(wsw + WS_ENC_H + tile * 512 + L * 8);
        bel[ntL][kt] = *(const f16x8*)(wsw + WS_ENC_L + tile * 512 + L * 8);
      }
    f32x4 a1[4][2], a2[4][2];
    #pragma unroll
    for (int mt = 0; mt < 4; ++mt)
      #pragma unroll
      for (int ntL = 0; ntL < 2; ++ntL) { a1[mt][ntL] = (f32x4)0.0f; a2[mt][ntL] = (f32x4)0.0f; }
    // two halves over mt; pah/pal registers reused between halves
    #pragma unroll
    for (int half = 0; half < 2; ++half) {
      f16x8 pah[2][2], pal[2][2];
      #pragma unroll
      for (int m = 0; m < 2; ++m)
        #pragma unroll
        for (int kt = 0; kt < 2; ++kt) {
          int off = ((half * 2 + m) * 16 + c) * 72 + kt * 32 + q * 8;
          pah[m][kt] = *(const f16x8*)(sPEh + off);
          pal[m][kt] = *(const f16x8*)(sPEl + off);
        }
      __builtin_amdgcn_s_setprio(1);
      #pragma unroll
      for (int kt = 0; kt < 2; ++kt)
        #pragma unroll
        for (int m = 0; m < 2; ++m)
          #pragma unroll
          for (int ntL = 0; ntL < 2; ++ntL) {
            int mt = half * 2 + m;
            a1[mt][ntL] = MFMA(pah[m][kt], beh[ntL][kt], a1[mt][ntL]);
            a2[mt][ntL] = MFMA(pah[m][kt], bel[ntL][kt], a2[mt][ntL]);
            a2[mt][ntL] = MFMA(pal[m][kt], beh[ntL][kt], a2[mt][ntL]);
          }
      __builtin_amdgcn_s_setprio(0);
      asm volatile("" ::: "memory");   // fence: keep halves' LDS loads apart
    }
    __syncthreads();                                 // (2) sPE reads done -> sYl writable
    float bb0 = b_enc[(2 * w) * 16 + c];
    float bb1 = b_enc[(2 * w + 1) * 16 + c];
    #pragma unroll
    for (int mt = 0; mt < 4; ++mt)
      #pragma unroll
      for (int ntL = 0; ntL < 2; ++ntL) {
        float bb = ntL ? bb1 : bb0;
        int col = (2 * w + ntL) * 16 + c;
        #pragma unroll
        for (int r = 0; r < 4; ++r) {
          float v = fmaxf(a1[mt][ntL][r] + a2[mt][ntL][r] * INV2048 + bb, 0.0f);
          int row = mt * 16 + q * 4 + r;
          _Float16 h = (_Float16)v;
          sYh[row * 136 + col] = h;
          sYl[row * 136 + col] = (_Float16)((v - (float)h) * 2048.0f);
        }
      }
  }
  __syncthreads();                                   // (3)

  // hoist Y hi frags for kt=0..2 only (48 VGPR); kt=3 + all lo re-read per use
  f16x8 Ah[4][3];
  #pragma unroll
  for (int nt = 0; nt < 4; ++nt)
    #pragma unroll
    for (int kt = 0; kt < 3; ++kt)
      Ah[nt][kt] = *(const f16x8*)(sYh + (nt * 16 + c) * 136 + kt * 32 + q * 8);
  const f32x4 wsv0 = *(const f32x4*)(w_sig + (2 * w) * 16 + q * 4);
  const f32x4 wsv1 = *(const f32x4*)(w_sig + (2 * w + 1) * 16 + q * 4);

  // ---- pass 1: 16-step (e,i) loop, single-buffered weights ----
  float psum[4] = {0.f, 0.f, 0.f, 0.f};

  #pragma unroll 1
  for (int s = 0; s < 16; ++s) {
    int e = s >> 1, i = s & 1;
    int tbase = (e * 8 + 2 * w + i) * 4;
    f16x8 bh[4], bl[4];
    #pragma unroll
    for (int kt = 0; kt < 4; ++kt) {
      bh[kt] = *(const f16x8*)(wsw + WS_SH_H + (tbase + kt) * 512 + L * 8);
      bl[kt] = *(const f16x8*)(wsw + WS_SH_L + (tbase + kt) * 512 + L * 8);
    }
    f32x4 bb = *(const f32x4*)(b_sh + e * 128 + (2 * w + i) * 16 + q * 4);

    f32x4 a1[4], a2[4];
    #pragma unroll
    for (int nt = 0; nt < 4; ++nt) { a1[nt] = (f32x4)0.0f; a2[nt] = (f32x4)0.0f; }
    __builtin_amdgcn_s_setprio(1);
    #pragma unroll
    for (int kt = 0; kt < 4; ++kt)
      #pragma unroll
      for (int nt = 0; nt < 4; ++nt) {
        f16x8 al = *(const f16x8*)(sYl + (nt * 16 + c) * 136 + kt * 32 + q * 8);
        f16x8 ah;
        if (kt < 3) ah = Ah[nt][kt];
        else        ah = *(const f16x8*)(sYh + (nt * 16 + c) * 136 + kt * 32 + q * 8);
        a1[nt] = MFMA(bh[kt], ah, a1[nt]);
        a2[nt] = MFMA(bl[kt], ah, a2[nt]);
        a2[nt] = MFMA(bh[kt], al, a2[nt]);
      }
    __builtin_amdgcn_s_setprio(0);
    f32x4 wv = (s & 1) ? wsv1 : wsv0;
    #pragma unroll
    for (int nt = 0; nt < 4; ++nt)
      #pragma unroll
      for (int r = 0; r < 4; ++r) {
        float sv = fmaxf(fmaf(a2[nt][r], INV2048, a1[nt][r]) + bb[r], 0.0f);
        psum[nt] = fmaf(sv, wv[r], psum[nt]);
      }
    if (s & 1) {                       // end of expert e
      #pragma unroll
      for (int nt = 0; nt < 4; ++nt) {
        float v = psum[nt];
        v += __shfl_xor(v, 16);
        v += __shfl_xor(v, 32);
        if (q == 0) atomicAdd(sRed + e * 64 + nt * 16 + c, v);
        psum[nt] = 0.f;
      }
    }
  }
  __syncthreads();                                   // (4) — only pass-1 barrier

  // ---- argmax: distributed, 4 threads/point x 2 experts, gumbel inline ----
  {
    int pt = t >> 2;
    int eb = (t & 3) * 2;
    float best = -1e30f, bsig = 0.0f;
    int bide = 0;
    const float bs = b_sig[0];
    #pragma unroll
    for (int j = 0; j < 2; ++j) {
      int e = eb + j;
      float s = sRed[e * 64 + pt];
      float dotv = s + bs;
      float sig = fmaxf(dotv, 0.0f) + log1pf(expf(-fabsf(dotv)));
      float z = logf(sig + 1e-10f) / 0.166667f;
      float score = z + gumbel_for((unsigned)((n0 + pt) * 8 + e));
      if (score > best) { best = score; bsig = sig; bide = e; }
    }
    #pragma unroll
    for (int m = 1; m <= 2; m <<= 1) {
      float oS  = __shfl_xor(best, m);
      float oSg = __shfl_xor(bsig, m);
      int   oI  = __shfl_xor(bide, m);
      if (oS > best || (oS == best && oI < bide)) { best = oS; bsig = oSg; bide = oI; }
    }
    if ((t & 3) == 0) {
      S_BID(pt) = bide;                // row-pad slot; sYl dead, sSB not yet
      out[(size_t)(n0 + pt) * 4 + 3] = bsig;
    }
  }
  __syncthreads();                                   // (5)

  // ---- bucket lists: wave-0 ballot build ----
  if (t < 64) {
    int bid = S_BID(t);
    unsigned long long below = t ? ((~0ULL) >> (64 - t)) : 0ULL;
    int off = 0;
    #pragma unroll
    for (int e = 0; e < 8; ++e) {
      unsigned long long m = __ballot(bid == e);
      int cnt = __popcll(m);
      if (t == e) { S_CNT(e) = cnt; S_OFF(e) = off; }
      if (bid == e) {
        int rank = __popcll(m & below);
        S_LIST(off + rank) = t;
      }
      off += cnt;
    }
  }
  __syncthreads();                                   // (6)

  // ---- pass 2a: viewdir PE into sSB + winner S recompute (transposed) ----
  for (int idx = t; idx < PT * 32; idx += NTH) {
    int s = idx >> 5, cc = idx & 31;
    int pt = S_LIST(s);
    const float* xr = x + (size_t)(n0 + pt) * 6 + 3;
    float v;
    if (cc < 3)       v = xr[cc];
    else if (cc < 15) { int g = cc - 3;  v = sinf(xr[g % 3] * (float)(1 << (g / 3))); }
    else if (cc < 27) { int g = cc - 15; v = cosf(xr[g % 3] * (float)(1 << (g / 3))); }
    else              v = 0.0f;
    sSB[s * 168 + 128 + cc] = (_Float16)v;
  }
  #pragma unroll 1
  for (int ei = 0; ei < 2; ++ei) {
    int e = 2 * w + ei;
    int cnt = S_CNT(e), off = S_OFF(e);
    for (int base = 0; base < cnt; base += 16) {
      int sidx = base + c; if (sidx >= cnt) sidx = cnt - 1;
      int pt = S_LIST(off + sidx);
      f16x8 yb[4];
      #pragma unroll
      for (int kt = 0; kt < 4; ++kt)
        yb[kt] = *(const f16x8*)(sYh + pt * 136 + kt * 32 + q * 8);
      f32x4 acc[8];
      #pragma unroll
      for (int jt = 0; jt < 8; ++jt) acc[jt] = (f32x4)0.0f;
      // jt split into 2 halves of 4: <=16 weight frags in flight (64 VGPR)
      #pragma unroll
      for (int jh = 0; jh < 2; ++jh) {
        __builtin_amdgcn_s_setprio(1);
        #pragma unroll
        for (int jt2 = 0; jt2 < 4; ++jt2) {
          int jt = jh * 4 + jt2;
          #pragma unroll
          for (int kt = 0; kt < 4; ++kt) {
            f16x8 a = *(const f16x8*)(wsw + WS_SH_H + ((e * 8 + jt) * 4 + kt) * 512 + L * 8);
            acc[jt] = MFMA(a, yb[kt], acc[jt]);
          }
        }
        __builtin_amdgcn_s_setprio(0);
        asm volatile("" ::: "memory"); // fence: limit weight-load hoisting
      }
      bool wr = (base + c) < cnt;
      int slot = off + base + c;
      #pragma unroll
      for (int jt = 0; jt < 8; ++jt) {
        f32x4 bb = *(const f32x4*)(b_sh + e * 128 + jt * 16 + q * 4);
        f16x4 v;
        #pragma unroll
        for (int r = 0; r < 4; ++r)
          v[r] = (_Float16)fmaxf(acc[jt][r] + bb[r], 0.0f);
        if (wr) *(f16x4*)(sSB + slot * 168 + jt * 16 + q * 4) = v;
      }
    }
  }
  __syncthreads();                                   // (7) sYh dead -> sH writable

  // ---- pass 2b: rgb layer 1 via MFMA ([S;vd] @ W_r1) ----
  #pragma unroll 1
  for (int ei = 0; ei < 2; ++ei) {
    int e = 2 * w + ei;
    int cnt = S_CNT(e), off = S_OFF(e);
    for (int base = 0; base < cnt; base += 16) {
      int sidx = base + c; if (sidx >= cnt) sidx = cnt - 1;
      int slot = off + sidx;
      f16x8 ag[5];
      #pragma unroll
      for (int kt = 0; kt < 5; ++kt)
        ag[kt] = *(const f16x8*)(sSB + slot * 168 + kt * 32 + q * 8);
      f32x4 hacc[4];
      #pragma unroll
      for (int nt = 0; nt < 4; ++nt) hacc[nt] = (f32x4)0.0f;
      // nt split into 2 halves of 2: <=10 weight frags in flight (40 VGPR)
      #pragma unroll
      for (int nh = 0; nh < 2; ++nh) {
        __builtin_amdgcn_s_setprio(1);
        #pragma unroll
        for (int nt2 = 0; nt2 < 2; ++nt2) {
          int nt = nh * 2 + nt2;
          #pragma unroll
          for (int kt = 0; kt < 5; ++kt) {
            f16x8 bf = *(const f16x8*)(wsw + WS_R1_H + ((e * 4 + nt) * 5 + kt) * 512 + L * 8);
            hacc[nt] = MFMA(ag[kt], bf, hacc[nt]);
          }
        }
        __builtin_amdgcn_s_setprio(0);
        asm volatile("" ::: "memory"); // fence: limit weight-load hoisting
      }
      #pragma unroll
      for (int nt = 0; nt < 4; ++nt) {
        float bb = b_r1[e * 64 + nt * 16 + c];
        #pragma unroll
        for (int r = 0; r < 4; ++r) {
          int m = q * 4 + r;
          if (base + m < cnt)
            sH[(off + base + m) * 68 + nt * 16 + c] = fmaxf(hacc[nt][r] + bb, 0.0f);
        }
      }
    }
  }
  __syncthreads();                                   // (8)

  // ---- layer 2: rgb = sigmoid(h @ W_r2 + b) ----
  if (t < 192) {
    int s = t / 3, o = t - s * 3;
    int pt = S_LIST(s);
    int e = S_BID(pt);
    float a = b_r2[e * 3 + o];
    const float* w2 = W_r2 + e * 192 + o;
    #pragma unroll
    for (int jj = 0; jj < 64; jj += 4) {
      f32x4 h4 = *(const f32x4*)(sH + s * 68 + jj);
      a = fmaf(h4.x, w2[jj * 3], a);
      a = fmaf(h4.y, w2[jj * 3 + 3], a);
      a = fmaf(h4.z, w2[jj * 3 + 6], a);
      a = fmaf(h4.w, w2[jj * 3 + 9], a);
    }
    out[(size_t)(n0 + pt) * 4 + o] = 1.0f / (1.0f + expf(-a));
  }
}

extern "C" void kernel_launch(void* const* d_in, const int* in_sizes, int n_in,
                              void* d_out, int out_size, void* d_ws, size_t ws_size,
                              hipStream_t stream) {
  (void)in_sizes; (void)n_in; (void)ws_size; (void)out_size;
  const float* x     = (const float*)d_in[0];
  const float* W_enc = (const float*)d_in[1];
  const float* b_enc = (const float*)d_in[2];
  const float* W_sh  = (const float*)d_in[3];
  const float* b_sh  = (const float*)d_in[4];
  const float* w_sig = (const float*)d_in[5];
  const float* b_sig = (const float*)d_in[6];
  const float* W_r1  = (const float*)d_in[7];
  const float* b_r1  = (const float*)d_in[8];
  const float* W_r2  = (const float*)d_in[9];
  const float* b_r2  = (const float*)d_in[10];
  _Float16* ws = (_Float16*)d_ws;     // needs 720896 B
  float* outp = (float*)d_out;
  prep_kernel<<<864, 256, 0, stream>>>(W_enc, W_sh, W_r1, ws);
  nerf_moe_kernel<<<NBLK, NTH, 0, stream>>>(x, b_enc, b_sh, w_sig, b_sig,
                                            b_r1, W_r2, b_r2, ws, outp);
}